// Round 11
// baseline (127.133 us; speedup 1.0000x reference)
//
#include <hip/hip_runtime.h>
#include <hip/hip_cooperative_groups.h>

namespace cg = cooperative_groups;

typedef __bf16 bf16x8 __attribute__((ext_vector_type(8)));
typedef float f32x4 __attribute__((ext_vector_type(4)));

#define TWO_LOG2E 2.88539008177792681f   // 2*log2(e): exp(2x) = exp2(x*TWO_LOG2E)

#define GLOADLDS16(g, l) __builtin_amdgcn_global_load_lds(                     \
    (const __attribute__((address_space(1))) void*)(g),                        \
    (__attribute__((address_space(3))) void*)(l), 16, 0, 0)

__device__ __forceinline__ unsigned f2bf(float f) {
    unsigned u = __float_as_uint(f);
    return (u + 0x7FFFu + ((u >> 16) & 1u)) >> 16;   // RNE
}

// ============ phase 1 (64-thr block): normalize 4 rows -> bf16 zn; zero S/out ==========
__device__ __forceinline__ void phase1(const float* __restrict__ z1,
                                       const float* __restrict__ z2,
                                       unsigned short* __restrict__ zn,
                                       float* __restrict__ S,
                                       float* __restrict__ out) {
    const int lane = threadIdx.x;
    const int b = blockIdx.x;                   // 2048 blocks
    if (lane < 4) S[(b << 2) + lane] = 0.f;
    if (b == 0 && lane == 0) out[0] = 0.f;
#pragma unroll
    for (int r = 0; r < 4; ++r) {
        int row = (b << 2) + r;
        const float* src = (row < 4096) ? (z1 + row * 256) : (z2 + (row - 4096) * 256);
        float4 v = ((const float4*)src)[lane];  // 64 lanes * 4 = 256
        float ss = v.x * v.x + v.y * v.y + v.z * v.z + v.w * v.w;
#pragma unroll
        for (int m = 32; m > 0; m >>= 1) ss += __shfl_xor(ss, m, 64);
        float sc = 1.0f / fmaxf(sqrtf(ss), 1e-8f);
        uint2 w;
        w.x = f2bf(v.x * sc) | (f2bf(v.y * sc) << 16);
        w.y = f2bf(v.z * sc) | (f2bf(v.w * sc) << 16);
        *(uint2*)(zn + row * 256 + (lane << 2)) = w;
    }
}

// ============ phase 2: barrier-free wave-autonomous sim-exp, depth-2 prefetch ===========
// Block = ONE wave; 2048 jobs = 128 row-strips(64) x 16 col-runs(512); 8 blocks/CU.
// A = 64 rows x K=256 in regs (128 VGPRs). B streams through a wave-private RING of
// THREE 4KB LDS buffers via global_load_lds, staged TWO chunks ahead; steady-state
// `s_waitcnt vmcnt(8)` (the 8 newest loads = 2 in-flight prefetches) guarantees the
// consumed chunk landed while never draining the pipeline (AITER-style). The compiler
// does NOT model the DMA->ds_read dependency — these explicit waits are load-bearing
// (R9's NaN). No __syncthreads anywhere.
__device__ __forceinline__ void phase2(const unsigned short* __restrict__ zn,
                                       float* __restrict__ S,
                                       unsigned short* __restrict__ Bs) {
    const int lane = threadIdx.x;
    const int q = lane >> 4, n16 = lane & 15;
    const int job = blockIdx.x;                 // 0..2047
    const int rowBase = (job >> 4) << 6;        // strip * 64
    const int colRun  = (job & 15) << 9;        // run * 512

    // A: 64 rows x K=256 in registers (frag: row=n16, k=q*8 within 32-elem step)
    bf16x8 a[4][8];
#pragma unroll
    for (int rt = 0; rt < 4; ++rt)
#pragma unroll
        for (int ks = 0; ks < 8; ++ks)
            a[rt][ks] = *(const bf16x8*)(zn + ((rowBase + (rt << 4) + n16) << 8)
                                            + (ks << 5) + (q << 3));

    // stage chunk m (col-chunk m>>2, k-chunk m&3) into LDS at element-offset `off`
    auto stage = [&](int m, int off) {
        const int colBase = colRun + ((m >> 2) << 5);
        const int koff = (m & 3) << 6;
        unsigned short* base = Bs + off;
#pragma unroll
        for (int p = 0; p < 4; ++p) {
            int s = (p << 6) + lane;            // 16B slot 0..255
            int c = s >> 3, d = s & 7;
            int k8 = d ^ (c & 7);               // XOR swizzle (conflict-free b128 reads)
            GLOADLDS16(zn + ((colBase + c) << 8) + koff + (k8 << 3), base + (s << 3));
        }
    };

    float rs[4][4];
#pragma unroll
    for (int i = 0; i < 4; ++i)
#pragma unroll
        for (int j = 0; j < 4; ++j) rs[i][j] = 0.f;

    // consume chunk at element-offset `off` into acc, using a-step (kc*2+ks)
    f32x4 acc[4][2];
    auto consume = [&](int off, int kc) {
        const unsigned short* bb = Bs + off;
#pragma unroll
        for (int ks = 0; ks < 2; ++ks) {
            bf16x8 bf[2];
#pragma unroll
            for (int ct = 0; ct < 2; ++ct) {
                int c  = (ct << 4) + n16;               // col 0..31
                int k8 = ((ks << 2) + q) ^ (c & 7);     // swizzled chunk
                bf[ct] = *(const bf16x8*)(bb + (((c << 3) + k8) << 3));
            }
#pragma unroll
            for (int rt = 0; rt < 4; ++rt)
#pragma unroll
                for (int ct = 0; ct < 2; ++ct)
                    acc[rt][ct] = __builtin_amdgcn_mfma_f32_16x16x32_bf16(
                        a[rt][(kc << 1) + ks], bf[ct], acc[rt][ct], 0, 0, 0);
        }
    };
    auto epilogue = [&]() {
#pragma unroll
        for (int rt = 0; rt < 4; ++rt)
#pragma unroll
            for (int ct = 0; ct < 2; ++ct)
#pragma unroll
                for (int r = 0; r < 4; ++r)
                    rs[rt][r] += __builtin_amdgcn_exp2f(acc[rt][ct][r] * TWO_LOG2E);
    };

    stage(0, 0);
    stage(1, 2048);
    int mp = 2;                                  // next chunk to stage
    int off_p = 4096, off_c = 0;                 // ring offsets (elements, 2048/buf)

    for (int cc = 0; cc < 15; ++cc) {            // main: always stage + vmcnt(8)
#pragma unroll
        for (int rt = 0; rt < 4; ++rt)
#pragma unroll
            for (int ct = 0; ct < 2; ++ct) acc[rt][ct] = (f32x4){0.f, 0.f, 0.f, 0.f};
#pragma unroll
        for (int kc = 0; kc < 4; ++kc) {
            stage(mp, off_p);
            asm volatile("s_waitcnt vmcnt(8)" ::: "memory");
            consume(off_c, kc);
            ++mp;
            off_p += 2048; if (off_p == 6144) off_p = 0;
            off_c += 2048; if (off_c == 6144) off_c = 0;
        }
        epilogue();
    }
    // peeled tail cc=15: chunks 60..63 (stage 62,63 then drain)
#pragma unroll
    for (int rt = 0; rt < 4; ++rt)
#pragma unroll
        for (int ct = 0; ct < 2; ++ct) acc[rt][ct] = (f32x4){0.f, 0.f, 0.f, 0.f};
    stage(62, off_p);
    asm volatile("s_waitcnt vmcnt(8)" ::: "memory");
    consume(off_c, 0);
    off_p += 2048; if (off_p == 6144) off_p = 0;
    off_c += 2048; if (off_c == 6144) off_c = 0;
    stage(63, off_p);
    asm volatile("s_waitcnt vmcnt(8)" ::: "memory");
    consume(off_c, 1);
    off_c += 2048; if (off_c == 6144) off_c = 0;
    asm volatile("s_waitcnt vmcnt(4)" ::: "memory");
    consume(off_c, 2);
    off_c += 2048; if (off_c == 6144) off_c = 0;
    asm volatile("s_waitcnt vmcnt(0)" ::: "memory");
    consume(off_c, 3);
    epilogue();

    // flush once per job (C/D layout: col=n16, row=q*4+r)
#pragma unroll
    for (int rt = 0; rt < 4; ++rt)
#pragma unroll
        for (int r = 0; r < 4; ++r) {
            float s = rs[rt][r];
            s += __shfl_xor(s, 1, 64);
            s += __shfl_xor(s, 2, 64);
            s += __shfl_xor(s, 4, 64);
            s += __shfl_xor(s, 8, 64);
            if (n16 == 0) atomicAdd(&S[rowBase + (rt << 4) + (q << 2) + r], s);
        }
}

// ============ phase 3 (64-thr block): loss over 4 rows, pure in-wave ====================
__device__ __forceinline__ void phase3(const unsigned short* __restrict__ zn,
                                       const float* __restrict__ S,
                                       float* __restrict__ out) {
    const int lane = threadIdx.x;
    const int q = lane >> 4, n16 = lane & 15;
    const int b = blockIdx.x;                   // 2048 blocks
    const int row = (b << 2) + q;               // quad q handles one row
    const int tar = (row + 4096) & 8191;

    float drr = 0.f, drt = 0.f;
#pragma unroll
    for (int i = 0; i < 4; ++i) {
        int k = (n16 << 4) + (i << 2);          // 16 elems/lane, 4 per uint2
        uint2 ur = *(const uint2*)(zn + (row << 8) + k);
        uint2 ut = *(const uint2*)(zn + (tar << 8) + k);
        float a0 = __uint_as_float(ur.x << 16),  a1 = __uint_as_float(ur.x & 0xFFFF0000u);
        float a2 = __uint_as_float(ur.y << 16),  a3 = __uint_as_float(ur.y & 0xFFFF0000u);
        float b0 = __uint_as_float(ut.x << 16),  b1 = __uint_as_float(ut.x & 0xFFFF0000u);
        float b2 = __uint_as_float(ut.y << 16),  b3 = __uint_as_float(ut.y & 0xFFFF0000u);
        drr += a0 * a0 + a1 * a1 + a2 * a2 + a3 * a3;
        drt += a0 * b0 + a1 * b1 + a2 * b2 + a3 * b3;
    }
#pragma unroll
    for (int m = 1; m <= 8; m <<= 1) {
        drr += __shfl_xor(drr, m, 64);
        drt += __shfl_xor(drt, m, 64);
    }
    float val = 0.f;
    if (n16 == 0) {
        float Sv = S[row] - __builtin_amdgcn_exp2f(drr * TWO_LOG2E);  // remove diagonal
        val = 0.693147180559945f * __builtin_amdgcn_logf(Sv) - 2.0f * drt;
    }
    val += __shfl_xor(val, 16, 64);
    val += __shfl_xor(val, 32, 64);
    if (lane == 0) atomicAdd(out, val * (1.0f / 8192.0f));
}

// ================= kernels ==============================================================
__global__ void __launch_bounds__(64, 2) ntxent_fused(
    const float* __restrict__ z1, const float* __restrict__ z2,
    unsigned short* __restrict__ zn, float* __restrict__ S, float* __restrict__ out)
{
    __shared__ __align__(16) unsigned short Bs[3][2048];   // 3 x 4 KB ring, wave-private
    phase1(z1, z2, zn, S, out);
    cg::this_grid().sync();
    phase2(zn, S, &Bs[0][0]);
    cg::this_grid().sync();
    phase3(zn, S, out);
}

__global__ void __launch_bounds__(64) norm_k(
    const float* __restrict__ z1, const float* __restrict__ z2,
    unsigned short* __restrict__ zn, float* __restrict__ S, float* __restrict__ out)
{ phase1(z1, z2, zn, S, out); }

__global__ void __launch_bounds__(64, 2) simexp_k(
    const unsigned short* __restrict__ zn, float* __restrict__ S)
{
    __shared__ __align__(16) unsigned short Bs[3][2048];
    phase2(zn, S, &Bs[0][0]);
}

__global__ void __launch_bounds__(64) finish_k(
    const unsigned short* __restrict__ zn, const float* __restrict__ S,
    float* __restrict__ out)
{ phase3(zn, S, out); }

extern "C" void kernel_launch(void* const* d_in, const int* in_sizes, int n_in,
                              void* d_out, int out_size, void* d_ws, size_t ws_size,
                              hipStream_t stream)
{
    const float* z1 = (const float*)d_in[0];
    const float* z2 = (const float*)d_in[1];
    unsigned short* zn = (unsigned short*)d_ws;                              // 4 MB
    float* S = (float*)((char*)d_ws + 8192 * 256 * sizeof(unsigned short));  // 32 KB
    float* out = (float*)d_out;

    // Host-only queries (graph-capture safe): need ALL 2048 one-wave blocks resident.
    int dev = 0;
    hipGetDevice(&dev);
    int coopOK = 0;
    hipDeviceGetAttribute(&coopOK, hipDeviceAttributeCooperativeLaunch, dev);
    int cus = 0;
    hipDeviceGetAttribute(&cus, hipDeviceAttributeMultiprocessorCount, dev);
    int maxB = 0;
    hipOccupancyMaxActiveBlocksPerMultiprocessor(&maxB, ntxent_fused, 64, 0);

    if (coopOK && (long long)maxB * cus >= 2048) {
        void* args[] = {(void*)&z1, (void*)&z2, (void*)&zn, (void*)&S, (void*)&out};
        hipError_t err = hipLaunchCooperativeKernel(ntxent_fused, dim3(2048), dim3(64),
                                                    args, 0, stream);
        if (err == hipSuccess) return;
    }
    // Fallback: the R10-proven 3-kernel pipeline (same phases, non-cooperative).
    norm_k<<<2048, 64, 0, stream>>>(z1, z2, zn, S, out);
    simexp_k<<<2048, 64, 0, stream>>>(zn, S);
    finish_k<<<2048, 64, 0, stream>>>(zn, S, out);
}

// Round 14
// 105.355 us; speedup vs baseline: 1.2067x; 1.2067x over previous
//
#include <hip/hip_runtime.h>

typedef __bf16 bf16x8 __attribute__((ext_vector_type(8)));
typedef float f32x4 __attribute__((ext_vector_type(4)));

#define TWO_LOG2E 2.88539008177792681f   // 2*log2(e): exp(2x) = exp2(x*TWO_LOG2E)

#define GLOADLDS16(g, l) __builtin_amdgcn_global_load_lds(                     \
    (const __attribute__((address_space(1))) void*)(g),                        \
    (__attribute__((address_space(3))) void*)(l), 16, 0, 0)

__device__ __forceinline__ unsigned f2bf(float f) {
    unsigned u = __float_as_uint(f);
    return (u + 0x7FFFu + ((u >> 16) & 1u)) >> 16;   // RNE
}

// ---------------- kernel 1: row-normalize z=[z1;z2] -> bf16 zn[8192][256] ---------------
// Blocks 0..31 also zero S[8192]; block 32 zeroes out[0]. (R10-proven form.)
__global__ void __launch_bounds__(256) normalize_kernel(
    const float* __restrict__ z1, const float* __restrict__ z2,
    unsigned short* __restrict__ zn, float* __restrict__ S, float* __restrict__ out)
{
    if (blockIdx.x < 32) S[(blockIdx.x << 8) + threadIdx.x] = 0.f;
    if (blockIdx.x == 32 && threadIdx.x == 0) out[0] = 0.f;

    const int wave = threadIdx.x >> 6, lane = threadIdx.x & 63;
    const int row = (blockIdx.x << 2) + wave;               // 2048 blocks * 4 rows
    const float* src = (row < 4096) ? (z1 + row * 256) : (z2 + (row - 4096) * 256);
    float4 v = ((const float4*)src)[lane];                  // 64 lanes * 4 = 256
    float ss = v.x * v.x + v.y * v.y + v.z * v.z + v.w * v.w;
#pragma unroll
    for (int m = 32; m > 0; m >>= 1) ss += __shfl_xor(ss, m, 64);
    float sc = 1.0f / fmaxf(sqrtf(ss), 1e-8f);
    uint2 w;
    w.x = f2bf(v.x * sc) | (f2bf(v.y * sc) << 16);
    w.y = f2bf(v.z * sc) | (f2bf(v.w * sc) << 16);
    *(uint2*)(zn + row * 256 + (lane << 2)) = w;
}

// ---------------- kernel 2: barrier-free wave-autonomous sim-exp, depth-3 prefetch ------
// R10's proven skeleton (107us total), single change: prefetch depth 2 -> 3 via a ring
// of FOUR 4KB wave-private LDS buffers; steady-state `s_waitcnt vmcnt(12)` (= 3 stages
// in flight) so each consumed chunk's loads are ~3 compute-intervals old. The explicit
// waits order global_load_lds DMA -> ds_read (compiler does NOT model it — R9's NaN).
// No __syncthreads anywhere. NO completion gate (R12/R13: gate => core dump, twice).
__global__ void __launch_bounds__(64, 2) simexp_kernel(
    const unsigned short* __restrict__ zn, float* __restrict__ S)
{
    __shared__ __align__(16) unsigned short Bs[4][2048];    // 4 x 4 KB ring, wave-private

    const int lane = threadIdx.x;
    const int q = lane >> 4, n16 = lane & 15;
    const int job = blockIdx.x;                 // 0..2047
    const int rowBase = (job >> 4) << 6;        // strip * 64
    const int colRun  = (job & 15) << 9;        // run * 512

    // A: 64 rows x K=256 in registers (frag: row=n16, k=q*8 within 32-elem step)
    bf16x8 a[4][8];
#pragma unroll
    for (int rt = 0; rt < 4; ++rt)
#pragma unroll
        for (int ks = 0; ks < 8; ++ks)
            a[rt][ks] = *(const bf16x8*)(zn + ((rowBase + (rt << 4) + n16) << 8)
                                            + (ks << 5) + (q << 3));

    // stage chunk m (col-chunk m>>2, k-chunk m&3) into LDS at element-offset `off`
    auto stage = [&](int m, int off) {
        const int colBase = colRun + ((m >> 2) << 5);
        const int koff = (m & 3) << 6;
        unsigned short* base = (unsigned short*)&Bs[0][0] + off;
#pragma unroll
        for (int p = 0; p < 4; ++p) {
            int s = (p << 6) + lane;            // 16B slot 0..255
            int c = s >> 3, d = s & 7;
            int k8 = d ^ (c & 7);               // XOR swizzle (conflict-free b128 reads)
            GLOADLDS16(zn + ((colBase + c) << 8) + koff + (k8 << 3), base + (s << 3));
        }
    };

    float rs[4][4];
#pragma unroll
    for (int i = 0; i < 4; ++i)
#pragma unroll
        for (int j = 0; j < 4; ++j) rs[i][j] = 0.f;

    // consume chunk at element-offset `off` into acc, using a-step (kc*2+ks)
    f32x4 acc[4][2];
    auto consume = [&](int off, int kc) {
        const unsigned short* bb = (const unsigned short*)&Bs[0][0] + off;
#pragma unroll
        for (int ks = 0; ks < 2; ++ks) {
            bf16x8 bf[2];
#pragma unroll
            for (int ct = 0; ct < 2; ++ct) {
                int c  = (ct << 4) + n16;               // col 0..31
                int k8 = ((ks << 2) + q) ^ (c & 7);     // swizzled chunk
                bf[ct] = *(const bf16x8*)(bb + (((c << 3) + k8) << 3));
            }
#pragma unroll
            for (int rt = 0; rt < 4; ++rt)
#pragma unroll
                for (int ct = 0; ct < 2; ++ct)
                    acc[rt][ct] = __builtin_amdgcn_mfma_f32_16x16x32_bf16(
                        a[rt][(kc << 1) + ks], bf[ct], acc[rt][ct], 0, 0, 0);
        }
    };
    auto epilogue = [&]() {
#pragma unroll
        for (int rt = 0; rt < 4; ++rt)
#pragma unroll
            for (int ct = 0; ct < 2; ++ct)
#pragma unroll
                for (int r = 0; r < 4; ++r)
                    rs[rt][r] += __builtin_amdgcn_exp2f(acc[rt][ct][r] * TWO_LOG2E);
    };

    stage(0, 0);
    stage(1, 2048);
    stage(2, 4096);
    int mp = 3;                                  // next chunk to stage
    int off_p = 6144, off_c = 0;                 // ring offsets (elements, 2048/buf)

    for (int cc = 0; cc < 15; ++cc) {            // main: always stage + vmcnt(12)
#pragma unroll
        for (int rt = 0; rt < 4; ++rt)
#pragma unroll
            for (int ct = 0; ct < 2; ++ct) acc[rt][ct] = (f32x4){0.f, 0.f, 0.f, 0.f};
#pragma unroll
        for (int kc = 0; kc < 4; ++kc) {
            stage(mp, off_p);
            asm volatile("s_waitcnt vmcnt(12)" ::: "memory");
            consume(off_c, kc);
            ++mp;
            off_p = (off_p + 2048) & 8191;
            off_c = (off_c + 2048) & 8191;
        }
        epilogue();
    }
    // peeled tail cc=15: chunks 60..63 (stage 63 then drain 12->8->4->0)
#pragma unroll
    for (int rt = 0; rt < 4; ++rt)
#pragma unroll
        for (int ct = 0; ct < 2; ++ct) acc[rt][ct] = (f32x4){0.f, 0.f, 0.f, 0.f};
    stage(63, off_p);
    asm volatile("s_waitcnt vmcnt(12)" ::: "memory");
    consume(off_c, 0);
    off_c = (off_c + 2048) & 8191;
    asm volatile("s_waitcnt vmcnt(8)" ::: "memory");
    consume(off_c, 1);
    off_c = (off_c + 2048) & 8191;
    asm volatile("s_waitcnt vmcnt(4)" ::: "memory");
    consume(off_c, 2);
    off_c = (off_c + 2048) & 8191;
    asm volatile("s_waitcnt vmcnt(0)" ::: "memory");
    consume(off_c, 3);
    epilogue();

    // flush once per job (C/D layout: col=n16, row=q*4+r)
#pragma unroll
    for (int rt = 0; rt < 4; ++rt)
#pragma unroll
        for (int r = 0; r < 4; ++r) {
            float s = rs[rt][r];
            s += __shfl_xor(s, 1, 64);
            s += __shfl_xor(s, 2, 64);
            s += __shfl_xor(s, 4, 64);
            s += __shfl_xor(s, 8, 64);
            if (n16 == 0) atomicAdd(&S[rowBase + (rt << 4) + (q << 2) + r], s);
        }
}

// ---------------- kernel 3: loss = mean( log(S_i - e^{sim_ii}) - sim_{i,target} ) -------
__global__ void __launch_bounds__(256) finish_kernel(
    const unsigned short* __restrict__ zn, const float* __restrict__ S,
    float* __restrict__ out)
{
    __shared__ float vals[16];
    const int tid = threadIdx.x, lane = tid & 63, wave = tid >> 6;
    const int q = lane >> 4, n16 = lane & 15;
    const int rib = (wave << 2) + q;                // 0..15 rows per block
    const int row = (blockIdx.x << 4) + rib;        // 512 blocks * 16 rows
    const int tar = (row + 4096) & 8191;

    float drr = 0.f, drt = 0.f;
#pragma unroll
    for (int i = 0; i < 4; ++i) {
        int k = (i << 6) + (n16 << 2);
        uint2 ur = *(const uint2*)(zn + (row << 8) + k);
        uint2 ut = *(const uint2*)(zn + (tar << 8) + k);
        float a0 = __uint_as_float(ur.x << 16),  a1 = __uint_as_float(ur.x & 0xFFFF0000u);
        float a2 = __uint_as_float(ur.y << 16),  a3 = __uint_as_float(ur.y & 0xFFFF0000u);
        float b0 = __uint_as_float(ut.x << 16),  b1 = __uint_as_float(ut.x & 0xFFFF0000u);
        float b2 = __uint_as_float(ut.y << 16),  b3 = __uint_as_float(ut.y & 0xFFFF0000u);
        drr += a0 * a0 + a1 * a1 + a2 * a2 + a3 * a3;
        drt += a0 * b0 + a1 * b1 + a2 * b2 + a3 * b3;
    }
#pragma unroll
    for (int m = 1; m <= 8; m <<= 1) {
        drr += __shfl_xor(drr, m, 64);
        drt += __shfl_xor(drt, m, 64);
    }
    if (n16 == 0) {
        float Sv = S[row] - __builtin_amdgcn_exp2f(drr * TWO_LOG2E);  // remove diagonal
        vals[rib] = 0.693147180559945f * __builtin_amdgcn_logf(Sv) - 2.0f * drt;
    }
    __syncthreads();
    if (tid == 0) {
        float s = 0.f;
#pragma unroll
        for (int i = 0; i < 16; ++i) s += vals[i];
        atomicAdd(out, s * (1.0f / 8192.0f));
    }
}

extern "C" void kernel_launch(void* const* d_in, const int* in_sizes, int n_in,
                              void* d_out, int out_size, void* d_ws, size_t ws_size,
                              hipStream_t stream)
{
    const float* z1 = (const float*)d_in[0];
    const float* z2 = (const float*)d_in[1];
    unsigned short* zn = (unsigned short*)d_ws;                              // 4 MB
    float* S = (float*)((char*)d_ws + 8192 * 256 * sizeof(unsigned short));  // 32 KB
    float* out = (float*)d_out;

    normalize_kernel<<<2048, 256, 0, stream>>>(z1, z2, zn, S, out);
    simexp_kernel<<<2048, 64, 0, stream>>>(zn, S);
    finish_kernel<<<512, 256, 0, stream>>>(zn, S, out);
}